// Round 2
// baseline (204.228 us; speedup 1.0000x reference)
//
#include <hip/hip_runtime.h>
#include <stdint.h>

// ---------------------------------------------------------------------------
// Patcher: bit-exact JAX threefry (PARTITIONABLE scheme, default since
// jax 0.4.30) + last-writer-wins composite.
// B=8, H=W=640, N=12 boxes, P=256 patch.
//
// Partitionable threefry:
//   split(key, n)[j]          = (o0,o1) of tf2x32(key, c0=0, c1=j)
//   random_bits(key,32,...)[i] = o0 ^ o1 of tf2x32(key, c0=0, c1=i)
//
// ws layout (float index): [0..31] = 16 doubles (sums: [b]=img, [8+b]=patch)
//                          [32..95] = per-image wmul[3],_,badd[3],_  (8 x 8)
//                          [96..1631] = per-box params (8*12*16 floats)
//                          [1664.. ] = adjusted patch p2 (8*256*256*3 floats)
// ---------------------------------------------------------------------------

#define IMG_ELEMS   1228800   // 640*640*3
#define NPIX        409600    // 640*640
#define PATCH_ELEMS 196608    // 256*256*3
#define WB_OFF 32
#define BP_OFF 96
#define P2_OFF 1664

#define TF_R(r) { x0 += x1; x1 = (x1 << r) | (x1 >> (32 - r)); x1 ^= x0; }

__device__ __forceinline__ void tf2x32(uint32_t k0, uint32_t k1,
                                       uint32_t c0, uint32_t c1,
                                       uint32_t& o0, uint32_t& o1) {
  uint32_t k2 = k0 ^ k1 ^ 0x1BD11BDAu;
  uint32_t x0 = c0 + k0, x1 = c1 + k1;
  TF_R(13) TF_R(15) TF_R(26) TF_R(6)
  x0 += k1; x1 += k2 + 1u;
  TF_R(17) TF_R(29) TF_R(16) TF_R(24)
  x0 += k2; x1 += k0 + 2u;
  TF_R(13) TF_R(15) TF_R(26) TF_R(6)
  x0 += k0; x1 += k1 + 3u;
  TF_R(17) TF_R(29) TF_R(16) TF_R(24)
  x0 += k1; x1 += k2 + 4u;
  TF_R(13) TF_R(15) TF_R(26) TF_R(6)
  x0 += k2; x1 += k0 + 5u;
  o0 = x0; o1 = x1;
}

// child key j of split(parent, n)  (foldlike / partitionable)
__device__ __forceinline__ void split_key(uint32_t k0, uint32_t k1, uint32_t j,
                                          uint32_t& o0, uint32_t& o1) {
  tf2x32(k0, k1, 0u, j, o0, o1);
}

// element i of random_bits(key, 32, shape) (partitionable: o0 ^ o1)
__device__ __forceinline__ uint32_t rbits32(uint32_t k0, uint32_t k1, uint32_t i) {
  uint32_t o0, o1;
  tf2x32(k0, k1, 0u, i, o0, o1);
  return o0 ^ o1;
}

__device__ __forceinline__ float u01(uint32_t bits) {
  return __uint_as_float((bits >> 9) | 0x3f800000u) - 1.0f;
}

// XLA ErfInv f32 (Giles) — value-level only (feeds wmul/badd normals)
__device__ __forceinline__ float erfinv_f(float x) {
  #pragma clang fp contract(off)
  float w = -log1pf(-(x * x));
  float p;
  if (w < 5.0f) {
    w = w - 2.5f;
    p = 2.81022636e-08f;
    p = 3.43273939e-07f + p * w;
    p = -3.5233877e-06f + p * w;
    p = -4.39150654e-06f + p * w;
    p = 0.00021858087f + p * w;
    p = -0.00125372503f + p * w;
    p = -0.00417768164f + p * w;
    p = 0.246640727f + p * w;
    p = 1.50140941f + p * w;
  } else {
    w = sqrtf(w) - 3.0f;
    p = -0.000200214257f;
    p = 0.000100950558f + p * w;
    p = 0.00134934322f + p * w;
    p = -0.00367342844f + p * w;
    p = 0.00573950773f + p * w;
    p = -0.0076224613f + p * w;
    p = 0.00943887047f + p * w;
    p = 1.00167406f + p * w;
    p = 2.83297682f + p * w;
  }
  return p * x;
}

// ---------------------------------------------------------------------------
// K1: per-image wmul/badd (tid<8) + per-box params (tid 32..127 -> 96 boxes)
// ---------------------------------------------------------------------------
__global__ __launch_bounds__(128) void k_params(const float* __restrict__ boxes,
                                                const float* __restrict__ scale_p,
                                                float* __restrict__ wsf) {
  #pragma clang fp contract(off)
  int tid = threadIdx.x;
  float scale = scale_p[0];
  if (tid < 8) {
    int b = tid;
    uint32_t ik0, ik1; split_key(0u, 42u, (uint32_t)b, ik0, ik1);
    uint32_t kw0, kw1; split_key(ik0, ik1, 0u, kw0, kw1);
    uint32_t kb0, kb1; split_key(ik0, ik1, 1u, kb0, kb1);
    const float lo  = __uint_as_float(0xBF7FFFFFu);   // nextafter(-1,0) f32
    const float SQ2 = (float)1.4142135623730951;
    for (int c = 0; c < 3; ++c) {
      float f  = u01(rbits32(kw0, kw1, (uint32_t)c));
      float u  = fmaxf(lo, __fadd_rn(__fmul_rn(f, 2.0f), lo));
      float n  = __fmul_rn(SQ2, erfinv_f(u));
      wsf[WB_OFF + b * 8 + c] = __fadd_rn(0.5f, __fmul_rn(0.1f, n));
      float f2 = u01(rbits32(kb0, kb1, (uint32_t)c));
      float u2 = fmaxf(lo, __fadd_rn(__fmul_rn(f2, 2.0f), lo));
      float n2 = __fmul_rn(SQ2, erfinv_f(u2));
      wsf[WB_OFF + b * 8 + 4 + c] = __fmul_rn(0.01f, n2);
    }
  }
  if (tid >= 32 && tid < 128) {
    int t = tid - 32;
    int b = t / 12, n = t % 12;
    uint32_t ik0, ik1; split_key(0u, 42u, (uint32_t)b, ik0, ik1);
    uint32_t ks0, ks1; split_key(ik0, ik1, 2u, ks0, ks1);
    uint32_t bk0, bk1; split_key(ks0, ks1, (uint32_t)n, bk0, bk1);
    uint32_t kc10, kc11; split_key(bk0, bk1, 0u, kc10, kc11);
    uint32_t kc20, kc21; split_key(bk0, bk1, 1u, kc20, kc21);
    uint32_t ka0,  ka1;  split_key(bk0, bk1, 2u, ka0,  ka1);
    uint32_t kd0,  kd1;  split_key(bk0, bk1, 3u, kd0,  kd1);
    uint32_t kn0,  kn1;  split_key(bk0, bk1, 4u, kn0,  kn1);

    const float* bx = boxes + (b * 12 + n) * 4;
    float ymin = bx[0], xmin = bx[1], ymax = bx[2], xmax = bx[3];
    float h  = __fsub_rn(ymax, ymin);
    float ww = __fsub_rn(xmax, xmin);
    float longer = fmaxf(h, ww);
    float patch_size = floorf(__fmul_rn(longer, scale));
    float diag = fminf(__fmul_rn((float)1.41421356237, patch_size), 640.0f);
    float u1 = u01(rbits32(kc10, kc11, 0u));
    float u2 = u01(rbits32(kc20, kc21, 0u));
    float jy = __fmul_rn(__fmul_rn(__fsub_rn(u1, 0.5f), 0.2f), h);
    float jx = __fmul_rn(__fmul_rn(__fsub_rn(u2, 0.5f), 0.2f), ww);
    float oy = __fadd_rn(__fadd_rn(ymin, __fmul_rn(h, 0.5f)), jy);
    float ox = __fadd_rn(__fadd_rn(xmin, __fmul_rn(ww, 0.5f)), jx);
    float ymin_p = fmaxf(__fsub_rn(oy, __fmul_rn(diag, 0.5f)), 0.0f);
    float xmin_p = fmaxf(__fsub_rn(ox, __fmul_rn(diag, 0.5f)), 0.0f);
    ymin_p = (__fadd_rn(ymin_p, diag) > 640.0f) ? __fsub_rn(640.0f, diag) : ymin_p;
    xmin_p = (__fadd_rn(xmin_p, diag) > 640.0f) ? __fsub_rn(640.0f, diag) : xmin_p;
    float valid = (__fmul_rn(patch_size, patch_size) > 4.0f) ? 1.0f : 0.0f;
    float y0f = floorf(ymin_p), x0f = floorf(xmin_p);
    float phf = patch_size, diagf = floorf(diag);
    float top = floorf(__fmul_rn(__fsub_rn(diagf, phf), 0.5f));
    float ua = u01(rbits32(ka0, ka1, 0u));
    float angle = __fmul_rn(__fsub_rn(__fmul_rn(ua, 2.0f), 1.0f),
                            (float)0.3490658503988659);
    float ud = u01(rbits32(kd0, kd1, 0u));
    float delta = __fmul_rn(__fsub_rn(__fmul_rn(ud, 2.0f), 1.0f), 0.3f);
    float cc = __fmul_rn(__fsub_rn(diagf, 1.0f), 0.5f);
    // f64 cos/sin rounded to f32 == correctly-rounded f32
    float ca = (float)cos((double)angle);
    float sa = (float)sin((double)angle);
    float safe_ph = fmaxf(phf, 1.0f);
    float q = __fdiv_rn(256.0f, safe_ph);

    float* Pp = wsf + BP_OFF + (b * 12 + n) * 16;
    Pp[0] = y0f;  Pp[1] = x0f;  Pp[2] = diagf; Pp[3] = phf;
    Pp[4] = top;  Pp[5] = cc;   Pp[6] = ca;    Pp[7] = sa;
    Pp[8] = delta; Pp[9] = valid;
    Pp[10] = __uint_as_float(kn0); Pp[11] = __uint_as_float(kn1);
    Pp[12] = q;
  }
}

// ---------------------------------------------------------------------------
// K2: per-image mean (f64 accumulate; value-level only)
// ---------------------------------------------------------------------------
__global__ __launch_bounds__(256) void k_mean_img(const float* __restrict__ img,
                                                  double* __restrict__ sums) {
  int b = blockIdx.y;
  const float* p = img + (size_t)b * IMG_ELEMS;
  double s = 0.0;
  for (uint32_t i = blockIdx.x * 256u + threadIdx.x; i < (uint32_t)IMG_ELEMS;
       i += 256u * gridDim.x)
    s += (double)p[i];
  __shared__ double sd[256];
  sd[threadIdx.x] = s;
  __syncthreads();
  for (int st = 128; st > 0; st >>= 1) {
    if ((int)threadIdx.x < st) sd[threadIdx.x] += sd[threadIdx.x + st];
    __syncthreads();
  }
  if (threadIdx.x == 0) atomicAdd(&sums[b], sd[0]);
}

// ---------------------------------------------------------------------------
// K3: p1 = clip(wmul*patch + badd, -1, 1)  (+ accumulate its sum)
// ---------------------------------------------------------------------------
__global__ __launch_bounds__(256) void k_p1(const float* __restrict__ patch,
                                            const float* __restrict__ wsf,
                                            float* __restrict__ p2,
                                            double* __restrict__ sums) {
  #pragma clang fp contract(off)
  int b = blockIdx.y;
  const float* wb = wsf + WB_OFF + b * 8;
  float wm0 = wb[0], wm1 = wb[1], wm2 = wb[2];
  float bd0 = wb[4], bd1 = wb[5], bd2 = wb[6];
  float* dst = p2 + (size_t)b * PATCH_ELEMS;
  double s = 0.0;
  for (uint32_t i = blockIdx.x * 256u + threadIdx.x; i < (uint32_t)PATCH_ELEMS;
       i += 256u * gridDim.x) {
    uint32_t c = i % 3u;
    float wm = (c == 0u) ? wm0 : ((c == 1u) ? wm1 : wm2);
    float bd = (c == 0u) ? bd0 : ((c == 1u) ? bd1 : bd2);
    float v = __fadd_rn(__fmul_rn(wm, patch[i]), bd);
    v = fminf(fmaxf(v, -1.0f), 1.0f);
    dst[i] = v;
    s += (double)v;
  }
  __shared__ double sd[256];
  sd[threadIdx.x] = s;
  __syncthreads();
  for (int st = 128; st > 0; st >>= 1) {
    if ((int)threadIdx.x < st) sd[threadIdx.x] += sd[threadIdx.x + st];
    __syncthreads();
  }
  if (threadIdx.x == 0) atomicAdd(&sums[8 + b], sd[0]);
}

// ---------------------------------------------------------------------------
// K4: p2 = clip(p1 + (mean_img - mean_p), -1, 1)
// ---------------------------------------------------------------------------
__global__ __launch_bounds__(256) void k_p2(float* __restrict__ p2,
                                            const double* __restrict__ sums) {
  #pragma clang fp contract(off)
  int b = blockIdx.y;
  float mi = (float)(sums[b] / (double)IMG_ELEMS);
  float mp = (float)(sums[8 + b] / (double)PATCH_ELEMS);
  float dm = __fsub_rn(mi, mp);
  float* dst = p2 + (size_t)b * PATCH_ELEMS;
  for (uint32_t i = blockIdx.x * 256u + threadIdx.x; i < (uint32_t)PATCH_ELEMS;
       i += 256u * gridDim.x) {
    float v = __fadd_rn(dst[i], dm);
    dst[i] = fminf(fmaxf(v, -1.0f), 1.0f);
  }
}

// ---------------------------------------------------------------------------
// K5: main composite — per pixel, last covering box wins.
// ---------------------------------------------------------------------------
__global__ __launch_bounds__(256) void k_main(const float* __restrict__ img,
                                              const float* __restrict__ params,
                                              const float* __restrict__ p2,
                                              float* __restrict__ out) {
  #pragma clang fp contract(off)
  __shared__ float bp[192];
  int b = blockIdx.y;
  if (threadIdx.x < 192) bp[threadIdx.x] = params[b * 192 + threadIdx.x];
  __syncthreads();
  int pix = blockIdx.x * 256 + threadIdx.x;
  int y = pix / 640;
  int x = pix - y * 640;
  float yf = (float)y, xf = (float)x;
  int winner = -1;
  float ry = 0.0f, rx = 0.0f;
  for (int n = 11; n >= 0; --n) {
    const float* Pp = &bp[n * 16];
    if (Pp[9] == 0.0f) continue;                        // valid_box
    float u = __fsub_rn(yf, Pp[0]);                     // exact
    float v = __fsub_rn(xf, Pp[1]);
    float diagf = Pp[2];
    if (!(u >= 0.0f && u < diagf && v >= 0.0f && v < diagf)) continue;
    float cc = Pp[5], ca = Pp[6], sa = Pp[7];
    float vc = __fsub_rn(v, cc), uc = __fsub_rn(u, cc);
    float sv = __fadd_rn(__fsub_rn(__fmul_rn(ca, vc), __fmul_rn(sa, uc)), cc);
    float su = __fadd_rn(__fadd_rn(__fmul_rn(sa, vc), __fmul_rn(ca, uc)), cc);
    float top = Pp[4], phf = Pp[3];
    float ry_ = __fsub_rn(su, top);
    float rx_ = __fsub_rn(sv, top);
    float ph1 = __fsub_rn(phf, 1.0f);
    if (!(ry_ >= 0.0f && ry_ <= ph1 && rx_ >= 0.0f && rx_ <= ph1)) continue;
    winner = n; ry = ry_; rx = rx_;
    break;
  }
  size_t base = ((size_t)b * NPIX + (size_t)pix) * 3u;
  float r0, r1, r2;
  if (winner < 0) {
    r0 = img[base]; r1 = img[base + 1]; r2 = img[base + 2];
  } else {
    const float* Pp = &bp[winner * 16];
    float q = Pp[12], delta = Pp[8];
    uint32_t kn0 = __float_as_uint(Pp[10]), kn1 = __float_as_uint(Pp[11]);
    float py = __fsub_rn(__fmul_rn(__fadd_rn(ry, 0.5f), q), 0.5f);
    float px = __fsub_rn(__fmul_rn(__fadd_rn(rx, 0.5f), q), 0.5f);
    float fy = floorf(py), fx = floorf(px);
    float wy = __fsub_rn(py, fy), wx = __fsub_rn(px, fx);
    int y0i = min(max((int)fy, 0), 255);
    int x0i = min(max((int)fx, 0), 255);
    int y1i = min(y0i + 1, 255);
    int x1i = min(x0i + 1, 255);
    const float* pb = p2 + (size_t)b * PATCH_ELEMS;
    int i00 = (y0i * 256 + x0i) * 3, i01 = (y0i * 256 + x1i) * 3;
    int i10 = (y1i * 256 + x0i) * 3, i11 = (y1i * 256 + x1i) * 3;
    float omwx = __fsub_rn(1.0f, wx), omwy = __fsub_rn(1.0f, wy);
    float res[3];
    for (int ch = 0; ch < 3; ++ch) {
      float v00 = pb[i00 + ch], v01 = pb[i01 + ch];
      float v10 = pb[i10 + ch], v11 = pb[i11 + ch];
      float t_ = __fadd_rn(__fmul_rn(omwx, v00), __fmul_rn(wx, v01));
      float b_ = __fadd_rn(__fmul_rn(omwx, v10), __fmul_rn(wx, v11));
      float bil = __fadd_rn(__fmul_rn(omwy, t_), __fmul_rn(wy, b_));
      uint32_t ni = (uint32_t)pix * 3u + (uint32_t)ch;
      float nf = u01(rbits32(kn0, kn1, ni));
      float noise = fmaxf(-0.01f, __fadd_rn(__fmul_rn(nf, 0.02f), -0.01f));
      float val = __fadd_rn(__fadd_rn(bil, noise), delta);
      res[ch] = fminf(fmaxf(val, -1.0f), 1.0f);
    }
    r0 = res[0]; r1 = res[1]; r2 = res[2];
  }
  out[base] = r0; out[base + 1] = r1; out[base + 2] = r2;
}

// ---------------------------------------------------------------------------
extern "C" void kernel_launch(void* const* d_in, const int* in_sizes, int n_in,
                              void* d_out, int out_size, void* d_ws, size_t ws_size,
                              hipStream_t stream) {
  const float* images = (const float*)d_in[0];
  const float* boxes  = (const float*)d_in[1];
  const float* patch  = (const float*)d_in[2];
  const float* scale  = (const float*)d_in[3];
  float* out = (float*)d_out;
  float* wsf = (float*)d_ws;
  double* sums = (double*)d_ws;
  float* p2 = wsf + P2_OFF;

  hipMemsetAsync(d_ws, 0, 16 * sizeof(double), stream);
  hipLaunchKernelGGL(k_params, dim3(1), dim3(128), 0, stream, boxes, scale, wsf);
  hipLaunchKernelGGL(k_mean_img, dim3(32, 8), dim3(256), 0, stream, images, sums);
  hipLaunchKernelGGL(k_p1, dim3(24, 8), dim3(256), 0, stream, patch, wsf, p2, sums);
  hipLaunchKernelGGL(k_p2, dim3(24, 8), dim3(256), 0, stream, p2, sums);
  hipLaunchKernelGGL(k_main, dim3(1600, 8), dim3(256), 0, stream,
                     images, wsf + BP_OFF, p2, out);
}

// Round 3
// 139.660 us; speedup vs baseline: 1.4623x; 1.4623x over previous
//
#include <hip/hip_runtime.h>
#include <stdint.h>

// ---------------------------------------------------------------------------
// Patcher: bit-exact JAX threefry (partitionable scheme) + last-writer-wins
// composite. B=8, H=W=640, N=12 boxes, P=256 patch.
//
// R3: perf pass. k_mean_img parallelized (float4 + 960 blocks, was 300 GB/s
// latency-bound at 256 blocks/scalar loads); p2 buffer eliminated — k_main
// recomputes clip(clip(wm*patch+bd)+dm) per tap; one fewer dispatch.
//
// ws layout (float idx): [0..31]  = 16 doubles (sums: [b]=img, [8+b]=patch-adj)
//                        [32..95] = per-image wmul[3],_,badd[3],_  (8 x 8)
//                        [96..1631] = per-box params (8*12*16 floats)
// ---------------------------------------------------------------------------

#define IMG_ELEMS   1228800   // 640*640*3
#define NPIX        409600    // 640*640
#define PATCH_ELEMS 196608    // 256*256*3
#define WB_OFF 32
#define BP_OFF 96

#define TF_R(r) { x0 += x1; x1 = (x1 << r) | (x1 >> (32 - r)); x1 ^= x0; }

__device__ __forceinline__ void tf2x32(uint32_t k0, uint32_t k1,
                                       uint32_t c0, uint32_t c1,
                                       uint32_t& o0, uint32_t& o1) {
  uint32_t k2 = k0 ^ k1 ^ 0x1BD11BDAu;
  uint32_t x0 = c0 + k0, x1 = c1 + k1;
  TF_R(13) TF_R(15) TF_R(26) TF_R(6)
  x0 += k1; x1 += k2 + 1u;
  TF_R(17) TF_R(29) TF_R(16) TF_R(24)
  x0 += k2; x1 += k0 + 2u;
  TF_R(13) TF_R(15) TF_R(26) TF_R(6)
  x0 += k0; x1 += k1 + 3u;
  TF_R(17) TF_R(29) TF_R(16) TF_R(24)
  x0 += k1; x1 += k2 + 4u;
  TF_R(13) TF_R(15) TF_R(26) TF_R(6)
  x0 += k2; x1 += k0 + 5u;
  o0 = x0; o1 = x1;
}

__device__ __forceinline__ void split_key(uint32_t k0, uint32_t k1, uint32_t j,
                                          uint32_t& o0, uint32_t& o1) {
  tf2x32(k0, k1, 0u, j, o0, o1);
}

__device__ __forceinline__ uint32_t rbits32(uint32_t k0, uint32_t k1, uint32_t i) {
  uint32_t o0, o1;
  tf2x32(k0, k1, 0u, i, o0, o1);
  return o0 ^ o1;
}

__device__ __forceinline__ float u01(uint32_t bits) {
  return __uint_as_float((bits >> 9) | 0x3f800000u) - 1.0f;
}

// XLA ErfInv f32 (Giles) — value-level only (feeds wmul/badd normals)
__device__ __forceinline__ float erfinv_f(float x) {
  #pragma clang fp contract(off)
  float w = -log1pf(-(x * x));
  float p;
  if (w < 5.0f) {
    w = w - 2.5f;
    p = 2.81022636e-08f;
    p = 3.43273939e-07f + p * w;
    p = -3.5233877e-06f + p * w;
    p = -4.39150654e-06f + p * w;
    p = 0.00021858087f + p * w;
    p = -0.00125372503f + p * w;
    p = -0.00417768164f + p * w;
    p = 0.246640727f + p * w;
    p = 1.50140941f + p * w;
  } else {
    w = sqrtf(w) - 3.0f;
    p = -0.000200214257f;
    p = 0.000100950558f + p * w;
    p = 0.00134934322f + p * w;
    p = -0.00367342844f + p * w;
    p = 0.00573950773f + p * w;
    p = -0.0076224613f + p * w;
    p = 0.00943887047f + p * w;
    p = 1.00167406f + p * w;
    p = 2.83297682f + p * w;
  }
  return p * x;
}

// ---------------------------------------------------------------------------
// K1: per-image wmul/badd (tid<8) + per-box params (tid 32..127 -> 96 boxes)
// ---------------------------------------------------------------------------
__global__ __launch_bounds__(128) void k_params(const float* __restrict__ boxes,
                                                const float* __restrict__ scale_p,
                                                float* __restrict__ wsf) {
  #pragma clang fp contract(off)
  int tid = threadIdx.x;
  float scale = scale_p[0];
  if (tid < 8) {
    int b = tid;
    uint32_t ik0, ik1; split_key(0u, 42u, (uint32_t)b, ik0, ik1);
    uint32_t kw0, kw1; split_key(ik0, ik1, 0u, kw0, kw1);
    uint32_t kb0, kb1; split_key(ik0, ik1, 1u, kb0, kb1);
    const float lo  = __uint_as_float(0xBF7FFFFFu);   // nextafter(-1,0) f32
    const float SQ2 = (float)1.4142135623730951;
    for (int c = 0; c < 3; ++c) {
      float f  = u01(rbits32(kw0, kw1, (uint32_t)c));
      float u  = fmaxf(lo, __fadd_rn(__fmul_rn(f, 2.0f), lo));
      float n  = __fmul_rn(SQ2, erfinv_f(u));
      wsf[WB_OFF + b * 8 + c] = __fadd_rn(0.5f, __fmul_rn(0.1f, n));
      float f2 = u01(rbits32(kb0, kb1, (uint32_t)c));
      float u2 = fmaxf(lo, __fadd_rn(__fmul_rn(f2, 2.0f), lo));
      float n2 = __fmul_rn(SQ2, erfinv_f(u2));
      wsf[WB_OFF + b * 8 + 4 + c] = __fmul_rn(0.01f, n2);
    }
  }
  if (tid >= 32 && tid < 128) {
    int t = tid - 32;
    int b = t / 12, n = t % 12;
    uint32_t ik0, ik1; split_key(0u, 42u, (uint32_t)b, ik0, ik1);
    uint32_t ks0, ks1; split_key(ik0, ik1, 2u, ks0, ks1);
    uint32_t bk0, bk1; split_key(ks0, ks1, (uint32_t)n, bk0, bk1);
    uint32_t kc10, kc11; split_key(bk0, bk1, 0u, kc10, kc11);
    uint32_t kc20, kc21; split_key(bk0, bk1, 1u, kc20, kc21);
    uint32_t ka0,  ka1;  split_key(bk0, bk1, 2u, ka0,  ka1);
    uint32_t kd0,  kd1;  split_key(bk0, bk1, 3u, kd0,  kd1);
    uint32_t kn0,  kn1;  split_key(bk0, bk1, 4u, kn0,  kn1);

    const float* bx = boxes + (b * 12 + n) * 4;
    float ymin = bx[0], xmin = bx[1], ymax = bx[2], xmax = bx[3];
    float h  = __fsub_rn(ymax, ymin);
    float ww = __fsub_rn(xmax, xmin);
    float longer = fmaxf(h, ww);
    float patch_size = floorf(__fmul_rn(longer, scale));
    float diag = fminf(__fmul_rn((float)1.41421356237, patch_size), 640.0f);
    float u1 = u01(rbits32(kc10, kc11, 0u));
    float u2 = u01(rbits32(kc20, kc21, 0u));
    float jy = __fmul_rn(__fmul_rn(__fsub_rn(u1, 0.5f), 0.2f), h);
    float jx = __fmul_rn(__fmul_rn(__fsub_rn(u2, 0.5f), 0.2f), ww);
    float oy = __fadd_rn(__fadd_rn(ymin, __fmul_rn(h, 0.5f)), jy);
    float ox = __fadd_rn(__fadd_rn(xmin, __fmul_rn(ww, 0.5f)), jx);
    float ymin_p = fmaxf(__fsub_rn(oy, __fmul_rn(diag, 0.5f)), 0.0f);
    float xmin_p = fmaxf(__fsub_rn(ox, __fmul_rn(diag, 0.5f)), 0.0f);
    ymin_p = (__fadd_rn(ymin_p, diag) > 640.0f) ? __fsub_rn(640.0f, diag) : ymin_p;
    xmin_p = (__fadd_rn(xmin_p, diag) > 640.0f) ? __fsub_rn(640.0f, diag) : xmin_p;
    float valid = (__fmul_rn(patch_size, patch_size) > 4.0f) ? 1.0f : 0.0f;
    float y0f = floorf(ymin_p), x0f = floorf(xmin_p);
    float phf = patch_size, diagf = floorf(diag);
    float top = floorf(__fmul_rn(__fsub_rn(diagf, phf), 0.5f));
    float ua = u01(rbits32(ka0, ka1, 0u));
    float angle = __fmul_rn(__fsub_rn(__fmul_rn(ua, 2.0f), 1.0f),
                            (float)0.3490658503988659);
    float ud = u01(rbits32(kd0, kd1, 0u));
    float delta = __fmul_rn(__fsub_rn(__fmul_rn(ud, 2.0f), 1.0f), 0.3f);
    float cc = __fmul_rn(__fsub_rn(diagf, 1.0f), 0.5f);
    float ca = (float)cos((double)angle);   // f64->f32 == correctly-rounded f32
    float sa = (float)sin((double)angle);
    float safe_ph = fmaxf(phf, 1.0f);
    float q = __fdiv_rn(256.0f, safe_ph);

    float* Pp = wsf + BP_OFF + (b * 12 + n) * 16;
    Pp[0] = y0f;  Pp[1] = x0f;  Pp[2] = diagf; Pp[3] = phf;
    Pp[4] = top;  Pp[5] = cc;   Pp[6] = ca;    Pp[7] = sa;
    Pp[8] = delta; Pp[9] = valid;
    Pp[10] = __uint_as_float(kn0); Pp[11] = __uint_as_float(kn1);
    Pp[12] = q;
  }
}

// ---------------------------------------------------------------------------
// K2: per-image mean — float4 loads, wave-shuffle f64 reduce, 120 blocks/img.
// ---------------------------------------------------------------------------
__global__ __launch_bounds__(256) void k_mean_img(const float4* __restrict__ img,
                                                  double* __restrict__ sums) {
  int b = blockIdx.y;
  const float4* p = img + (size_t)b * (IMG_ELEMS / 4);
  double s = 0.0;
  const uint32_t stride = 256u * gridDim.x;
  for (uint32_t i = blockIdx.x * 256u + threadIdx.x; i < (uint32_t)(IMG_ELEMS / 4);
       i += stride) {
    float4 v = p[i];
    s += (double)v.x + (double)v.y + (double)v.z + (double)v.w;
  }
  for (int off = 32; off > 0; off >>= 1) s += __shfl_down(s, off, 64);
  __shared__ double sd[4];
  if ((threadIdx.x & 63u) == 0u) sd[threadIdx.x >> 6] = s;
  __syncthreads();
  if (threadIdx.x == 0)
    atomicAdd(&sums[b], sd[0] + sd[1] + sd[2] + sd[3]);
}

// ---------------------------------------------------------------------------
// K3: sum of p1 = clip(wmul*patch + badd, -1, 1) per image (no materialize).
// ---------------------------------------------------------------------------
__global__ __launch_bounds__(256) void k_sum_p1(const float4* __restrict__ patch,
                                                const float* __restrict__ wsf,
                                                double* __restrict__ sums) {
  #pragma clang fp contract(off)
  int b = blockIdx.y;
  const float* wb = wsf + WB_OFF + b * 8;
  float wm[3] = {wb[0], wb[1], wb[2]};
  float bd[3] = {wb[4], wb[5], wb[6]};
  double s = 0.0;
  const uint32_t stride = 256u * gridDim.x;
  for (uint32_t i = blockIdx.x * 256u + threadIdx.x; i < (uint32_t)(PATCH_ELEMS / 4);
       i += stride) {
    float4 v = patch[i];
    uint32_t c = (4u * i) % 3u;
    float f[4] = {v.x, v.y, v.z, v.w};
    #pragma unroll
    for (int j = 0; j < 4; ++j) {
      float val = __fadd_rn(__fmul_rn(wm[c], f[j]), bd[c]);
      val = fminf(fmaxf(val, -1.0f), 1.0f);
      s += (double)val;
      c = (c == 2u) ? 0u : (c + 1u);
    }
  }
  for (int off = 32; off > 0; off >>= 1) s += __shfl_down(s, off, 64);
  __shared__ double sd[4];
  if ((threadIdx.x & 63u) == 0u) sd[threadIdx.x >> 6] = s;
  __syncthreads();
  if (threadIdx.x == 0)
    atomicAdd(&sums[8 + b], sd[0] + sd[1] + sd[2] + sd[3]);
}

// ---------------------------------------------------------------------------
// K4: main composite — per pixel, last covering box wins. Patch-adjust
// (clip(wm*patch+bd)+dm, clip) recomputed per bilinear tap (patch L2-resident).
// ---------------------------------------------------------------------------
__global__ __launch_bounds__(256) void k_main(const float* __restrict__ img,
                                              const float* __restrict__ params,
                                              const float* __restrict__ wsf,
                                              const double* __restrict__ sums,
                                              const float* __restrict__ patch,
                                              float* __restrict__ out) {
  #pragma clang fp contract(off)
  __shared__ float bp[192];
  int b = blockIdx.y;
  if (threadIdx.x < 192) bp[threadIdx.x] = params[b * 192 + threadIdx.x];
  __syncthreads();
  int pix = blockIdx.x * 256 + threadIdx.x;
  int y = pix / 640;
  int x = pix - y * 640;
  float yf = (float)y, xf = (float)x;
  int winner = -1;
  float ry = 0.0f, rx = 0.0f;
  for (int n = 11; n >= 0; --n) {
    const float* Pp = &bp[n * 16];
    if (Pp[9] == 0.0f) continue;                        // valid_box
    float u = __fsub_rn(yf, Pp[0]);                     // exact (ints)
    float v = __fsub_rn(xf, Pp[1]);
    float diagf = Pp[2];
    if (!(u >= 0.0f && u < diagf && v >= 0.0f && v < diagf)) continue;
    float cc = Pp[5], ca = Pp[6], sa = Pp[7];
    float vc = __fsub_rn(v, cc), uc = __fsub_rn(u, cc);
    float sv = __fadd_rn(__fsub_rn(__fmul_rn(ca, vc), __fmul_rn(sa, uc)), cc);
    float su = __fadd_rn(__fadd_rn(__fmul_rn(sa, vc), __fmul_rn(ca, uc)), cc);
    float top = Pp[4], phf = Pp[3];
    float ry_ = __fsub_rn(su, top);
    float rx_ = __fsub_rn(sv, top);
    float ph1 = __fsub_rn(phf, 1.0f);
    if (!(ry_ >= 0.0f && ry_ <= ph1 && rx_ >= 0.0f && rx_ <= ph1)) continue;
    winner = n; ry = ry_; rx = rx_;
    break;
  }
  size_t base = ((size_t)b * NPIX + (size_t)pix) * 3u;
  float r0, r1, r2;
  if (winner < 0) {
    r0 = img[base]; r1 = img[base + 1]; r2 = img[base + 2];
  } else {
    const float* Pp = &bp[winner * 16];
    float q = Pp[12], delta = Pp[8];
    uint32_t kn0 = __float_as_uint(Pp[10]), kn1 = __float_as_uint(Pp[11]);
    // per-image patch-adjust params
    const float* wb = wsf + WB_OFF + b * 8;
    float mi = (float)(sums[b] / (double)IMG_ELEMS);
    float mp = (float)(sums[8 + b] / (double)PATCH_ELEMS);
    float dm = __fsub_rn(mi, mp);
    float py = __fsub_rn(__fmul_rn(__fadd_rn(ry, 0.5f), q), 0.5f);
    float px = __fsub_rn(__fmul_rn(__fadd_rn(rx, 0.5f), q), 0.5f);
    float fy = floorf(py), fx = floorf(px);
    float wy = __fsub_rn(py, fy), wx = __fsub_rn(px, fx);
    int y0i = min(max((int)fy, 0), 255);
    int x0i = min(max((int)fx, 0), 255);
    int y1i = min(y0i + 1, 255);
    int x1i = min(x0i + 1, 255);
    int i00 = (y0i * 256 + x0i) * 3, i01 = (y0i * 256 + x1i) * 3;
    int i10 = (y1i * 256 + x0i) * 3, i11 = (y1i * 256 + x1i) * 3;
    float omwx = __fsub_rn(1.0f, wx), omwy = __fsub_rn(1.0f, wy);
    float res[3];
    #pragma unroll
    for (int ch = 0; ch < 3; ++ch) {
      float wmc = wb[ch], bdc = wb[4 + ch];
      // p2 value at each tap: clip(clip(wm*patch+bd) + dm)
      float v00 = fminf(fmaxf(__fadd_rn(fminf(fmaxf(__fadd_rn(__fmul_rn(wmc, patch[i00 + ch]), bdc), -1.0f), 1.0f), dm), -1.0f), 1.0f);
      float v01 = fminf(fmaxf(__fadd_rn(fminf(fmaxf(__fadd_rn(__fmul_rn(wmc, patch[i01 + ch]), bdc), -1.0f), 1.0f), dm), -1.0f), 1.0f);
      float v10 = fminf(fmaxf(__fadd_rn(fminf(fmaxf(__fadd_rn(__fmul_rn(wmc, patch[i10 + ch]), bdc), -1.0f), 1.0f), dm), -1.0f), 1.0f);
      float v11 = fminf(fmaxf(__fadd_rn(fminf(fmaxf(__fadd_rn(__fmul_rn(wmc, patch[i11 + ch]), bdc), -1.0f), 1.0f), dm), -1.0f), 1.0f);
      float t_ = __fadd_rn(__fmul_rn(omwx, v00), __fmul_rn(wx, v01));
      float b_ = __fadd_rn(__fmul_rn(omwx, v10), __fmul_rn(wx, v11));
      float bil = __fadd_rn(__fmul_rn(omwy, t_), __fmul_rn(wy, b_));
      uint32_t ni = (uint32_t)pix * 3u + (uint32_t)ch;
      float nf = u01(rbits32(kn0, kn1, ni));
      float noise = fmaxf(-0.01f, __fadd_rn(__fmul_rn(nf, 0.02f), -0.01f));
      float val = __fadd_rn(__fadd_rn(bil, noise), delta);
      res[ch] = fminf(fmaxf(val, -1.0f), 1.0f);
    }
    r0 = res[0]; r1 = res[1]; r2 = res[2];
  }
  out[base] = r0; out[base + 1] = r1; out[base + 2] = r2;
}

// ---------------------------------------------------------------------------
extern "C" void kernel_launch(void* const* d_in, const int* in_sizes, int n_in,
                              void* d_out, int out_size, void* d_ws, size_t ws_size,
                              hipStream_t stream) {
  const float* images = (const float*)d_in[0];
  const float* boxes  = (const float*)d_in[1];
  const float* patch  = (const float*)d_in[2];
  const float* scale  = (const float*)d_in[3];
  float* out = (float*)d_out;
  float* wsf = (float*)d_ws;
  double* sums = (double*)d_ws;

  hipMemsetAsync(d_ws, 0, 16 * sizeof(double), stream);
  hipLaunchKernelGGL(k_params, dim3(1), dim3(128), 0, stream, boxes, scale, wsf);
  hipLaunchKernelGGL(k_mean_img, dim3(120, 8), dim3(256), 0, stream,
                     (const float4*)images, sums);
  hipLaunchKernelGGL(k_sum_p1, dim3(24, 8), dim3(256), 0, stream,
                     (const float4*)patch, wsf, sums);
  hipLaunchKernelGGL(k_main, dim3(1600, 8), dim3(256), 0, stream,
                     images, wsf + BP_OFF, wsf, sums, patch, out);
}

// Round 4
// 137.128 us; speedup vs baseline: 1.4893x; 1.0185x over previous
//
#include <hip/hip_runtime.h>
#include <stdint.h>

// ---------------------------------------------------------------------------
// Patcher: bit-exact JAX threefry (partitionable scheme) + last-writer-wins
// composite. B=8, H=W=640, N=12 boxes, P=256 patch.
//
// R4: 3 dispatches (was 6). k_params zeroes sums; k_sums fuses img-mean +
// patch-adjust-sum; k_main does 4 pixels/thread (float4 I/O) with per-block
// y-culled candidate box list in LDS. Per-pixel float math unchanged.
//
// ws layout (float idx): [0..31]  = 16 doubles (sums: [b]=img, [8+b]=patch-adj)
//                        [32..95] = per-image wmul[3],_,badd[3],_  (8 x 8)
//                        [96..1631] = per-box params (8*12*16 floats)
// ---------------------------------------------------------------------------

#define IMG_ELEMS   1228800   // 640*640*3
#define NPIX        409600    // 640*640
#define PATCH_ELEMS 196608    // 256*256*3
#define WB_OFF 32
#define BP_OFF 96

#define TF_R(r) { x0 += x1; x1 = (x1 << r) | (x1 >> (32 - r)); x1 ^= x0; }

__device__ __forceinline__ void tf2x32(uint32_t k0, uint32_t k1,
                                       uint32_t c0, uint32_t c1,
                                       uint32_t& o0, uint32_t& o1) {
  uint32_t k2 = k0 ^ k1 ^ 0x1BD11BDAu;
  uint32_t x0 = c0 + k0, x1 = c1 + k1;
  TF_R(13) TF_R(15) TF_R(26) TF_R(6)
  x0 += k1; x1 += k2 + 1u;
  TF_R(17) TF_R(29) TF_R(16) TF_R(24)
  x0 += k2; x1 += k0 + 2u;
  TF_R(13) TF_R(15) TF_R(26) TF_R(6)
  x0 += k0; x1 += k1 + 3u;
  TF_R(17) TF_R(29) TF_R(16) TF_R(24)
  x0 += k1; x1 += k2 + 4u;
  TF_R(13) TF_R(15) TF_R(26) TF_R(6)
  x0 += k2; x1 += k0 + 5u;
  o0 = x0; o1 = x1;
}

__device__ __forceinline__ void split_key(uint32_t k0, uint32_t k1, uint32_t j,
                                          uint32_t& o0, uint32_t& o1) {
  tf2x32(k0, k1, 0u, j, o0, o1);
}

__device__ __forceinline__ uint32_t rbits32(uint32_t k0, uint32_t k1, uint32_t i) {
  uint32_t o0, o1;
  tf2x32(k0, k1, 0u, i, o0, o1);
  return o0 ^ o1;
}

__device__ __forceinline__ float u01(uint32_t bits) {
  return __uint_as_float((bits >> 9) | 0x3f800000u) - 1.0f;
}

// XLA ErfInv f32 (Giles) — value-level only (feeds wmul/badd normals)
__device__ __forceinline__ float erfinv_f(float x) {
  #pragma clang fp contract(off)
  float w = -log1pf(-(x * x));
  float p;
  if (w < 5.0f) {
    w = w - 2.5f;
    p = 2.81022636e-08f;
    p = 3.43273939e-07f + p * w;
    p = -3.5233877e-06f + p * w;
    p = -4.39150654e-06f + p * w;
    p = 0.00021858087f + p * w;
    p = -0.00125372503f + p * w;
    p = -0.00417768164f + p * w;
    p = 0.246640727f + p * w;
    p = 1.50140941f + p * w;
  } else {
    w = sqrtf(w) - 3.0f;
    p = -0.000200214257f;
    p = 0.000100950558f + p * w;
    p = 0.00134934322f + p * w;
    p = -0.00367342844f + p * w;
    p = 0.00573950773f + p * w;
    p = -0.0076224613f + p * w;
    p = 0.00943887047f + p * w;
    p = 1.00167406f + p * w;
    p = 2.83297682f + p * w;
  }
  return p * x;
}

// ---------------------------------------------------------------------------
// K1: zero sums (tid 8..23) + per-image wmul/badd (tid<8) + per-box params
// (tid 32..127 -> 96 boxes)
// ---------------------------------------------------------------------------
__global__ __launch_bounds__(128) void k_params(const float* __restrict__ boxes,
                                                const float* __restrict__ scale_p,
                                                float* __restrict__ wsf) {
  #pragma clang fp contract(off)
  int tid = threadIdx.x;
  float scale = scale_p[0];
  if (tid >= 8 && tid < 24) ((double*)wsf)[tid - 8] = 0.0;
  if (tid < 8) {
    int b = tid;
    uint32_t ik0, ik1; split_key(0u, 42u, (uint32_t)b, ik0, ik1);
    uint32_t kw0, kw1; split_key(ik0, ik1, 0u, kw0, kw1);
    uint32_t kb0, kb1; split_key(ik0, ik1, 1u, kb0, kb1);
    const float lo  = __uint_as_float(0xBF7FFFFFu);   // nextafter(-1,0) f32
    const float SQ2 = (float)1.4142135623730951;
    for (int c = 0; c < 3; ++c) {
      float f  = u01(rbits32(kw0, kw1, (uint32_t)c));
      float u  = fmaxf(lo, __fadd_rn(__fmul_rn(f, 2.0f), lo));
      float n  = __fmul_rn(SQ2, erfinv_f(u));
      wsf[WB_OFF + b * 8 + c] = __fadd_rn(0.5f, __fmul_rn(0.1f, n));
      float f2 = u01(rbits32(kb0, kb1, (uint32_t)c));
      float u2 = fmaxf(lo, __fadd_rn(__fmul_rn(f2, 2.0f), lo));
      float n2 = __fmul_rn(SQ2, erfinv_f(u2));
      wsf[WB_OFF + b * 8 + 4 + c] = __fmul_rn(0.01f, n2);
    }
  }
  if (tid >= 32 && tid < 128) {
    int t = tid - 32;
    int b = t / 12, n = t % 12;
    uint32_t ik0, ik1; split_key(0u, 42u, (uint32_t)b, ik0, ik1);
    uint32_t ks0, ks1; split_key(ik0, ik1, 2u, ks0, ks1);
    uint32_t bk0, bk1; split_key(ks0, ks1, (uint32_t)n, bk0, bk1);
    uint32_t kc10, kc11; split_key(bk0, bk1, 0u, kc10, kc11);
    uint32_t kc20, kc21; split_key(bk0, bk1, 1u, kc20, kc21);
    uint32_t ka0,  ka1;  split_key(bk0, bk1, 2u, ka0,  ka1);
    uint32_t kd0,  kd1;  split_key(bk0, bk1, 3u, kd0,  kd1);
    uint32_t kn0,  kn1;  split_key(bk0, bk1, 4u, kn0,  kn1);

    const float* bx = boxes + (b * 12 + n) * 4;
    float ymin = bx[0], xmin = bx[1], ymax = bx[2], xmax = bx[3];
    float h  = __fsub_rn(ymax, ymin);
    float ww = __fsub_rn(xmax, xmin);
    float longer = fmaxf(h, ww);
    float patch_size = floorf(__fmul_rn(longer, scale));
    float diag = fminf(__fmul_rn((float)1.41421356237, patch_size), 640.0f);
    float u1 = u01(rbits32(kc10, kc11, 0u));
    float u2 = u01(rbits32(kc20, kc21, 0u));
    float jy = __fmul_rn(__fmul_rn(__fsub_rn(u1, 0.5f), 0.2f), h);
    float jx = __fmul_rn(__fmul_rn(__fsub_rn(u2, 0.5f), 0.2f), ww);
    float oy = __fadd_rn(__fadd_rn(ymin, __fmul_rn(h, 0.5f)), jy);
    float ox = __fadd_rn(__fadd_rn(xmin, __fmul_rn(ww, 0.5f)), jx);
    float ymin_p = fmaxf(__fsub_rn(oy, __fmul_rn(diag, 0.5f)), 0.0f);
    float xmin_p = fmaxf(__fsub_rn(ox, __fmul_rn(diag, 0.5f)), 0.0f);
    ymin_p = (__fadd_rn(ymin_p, diag) > 640.0f) ? __fsub_rn(640.0f, diag) : ymin_p;
    xmin_p = (__fadd_rn(xmin_p, diag) > 640.0f) ? __fsub_rn(640.0f, diag) : xmin_p;
    float valid = (__fmul_rn(patch_size, patch_size) > 4.0f) ? 1.0f : 0.0f;
    float y0f = floorf(ymin_p), x0f = floorf(xmin_p);
    float phf = patch_size, diagf = floorf(diag);
    float top = floorf(__fmul_rn(__fsub_rn(diagf, phf), 0.5f));
    float ua = u01(rbits32(ka0, ka1, 0u));
    float angle = __fmul_rn(__fsub_rn(__fmul_rn(ua, 2.0f), 1.0f),
                            (float)0.3490658503988659);
    float ud = u01(rbits32(kd0, kd1, 0u));
    float delta = __fmul_rn(__fsub_rn(__fmul_rn(ud, 2.0f), 1.0f), 0.3f);
    float cc = __fmul_rn(__fsub_rn(diagf, 1.0f), 0.5f);
    float ca = (float)cos((double)angle);   // f64->f32 == correctly-rounded f32
    float sa = (float)sin((double)angle);
    float safe_ph = fmaxf(phf, 1.0f);
    float q = __fdiv_rn(256.0f, safe_ph);

    float* Pp = wsf + BP_OFF + (b * 12 + n) * 16;
    Pp[0] = y0f;  Pp[1] = x0f;  Pp[2] = diagf; Pp[3] = phf;
    Pp[4] = top;  Pp[5] = cc;   Pp[6] = ca;    Pp[7] = sa;
    Pp[8] = delta; Pp[9] = valid;
    Pp[10] = __uint_as_float(kn0); Pp[11] = __uint_as_float(kn1);
    Pp[12] = q;
  }
}

// ---------------------------------------------------------------------------
// K2: fused sums. blockIdx.x<120: image mean chunks; >=120 (8 blocks):
// sum of clip(wmul*patch+badd,-1,1). f64 accumulate (value-level only).
// ---------------------------------------------------------------------------
__global__ __launch_bounds__(256) void k_sums(const float4* __restrict__ img,
                                              const float4* __restrict__ patch,
                                              const float* __restrict__ wsf,
                                              double* __restrict__ sums) {
  #pragma clang fp contract(off)
  int b = blockIdx.y;
  double s = 0.0;
  int slot;
  if (blockIdx.x < 120) {
    slot = b;
    const float4* p = img + (size_t)b * (IMG_ELEMS / 4);
    const uint32_t stride = 120u * 256u;
    for (uint32_t i = blockIdx.x * 256u + threadIdx.x;
         i < (uint32_t)(IMG_ELEMS / 4); i += stride) {
      float4 v = p[i];
      s += (double)v.x + (double)v.y + (double)v.z + (double)v.w;
    }
  } else {
    slot = 8 + b;
    const float* wb = wsf + WB_OFF + b * 8;
    float wm[3] = {wb[0], wb[1], wb[2]};
    float bd[3] = {wb[4], wb[5], wb[6]};
    const uint32_t stride = 8u * 256u;
    for (uint32_t i = (blockIdx.x - 120u) * 256u + threadIdx.x;
         i < (uint32_t)(PATCH_ELEMS / 4); i += stride) {
      float4 v = patch[i];
      uint32_t c = (4u * i) % 3u;
      float f[4] = {v.x, v.y, v.z, v.w};
      #pragma unroll
      for (int j = 0; j < 4; ++j) {
        float val = __fadd_rn(__fmul_rn(wm[c], f[j]), bd[c]);
        val = fminf(fmaxf(val, -1.0f), 1.0f);
        s += (double)val;
        c = (c == 2u) ? 0u : (c + 1u);
      }
    }
  }
  for (int off = 32; off > 0; off >>= 1) s += __shfl_down(s, off, 64);
  __shared__ double sd[4];
  if ((threadIdx.x & 63u) == 0u) sd[threadIdx.x >> 6] = s;
  __syncthreads();
  if (threadIdx.x == 0)
    atomicAdd(&sums[slot], sd[0] + sd[1] + sd[2] + sd[3]);
}

// ---------------------------------------------------------------------------
// K3: main composite — 4 pixels/thread (row-aligned since 640%4==0),
// float4 I/O, per-block y-culled candidate box list. Last covering box wins;
// patch-adjust recomputed per tap (patch L2-resident).
// ---------------------------------------------------------------------------
__global__ __launch_bounds__(256) void k_main(const float4* __restrict__ img4,
                                              const float* __restrict__ params,
                                              const float* __restrict__ wsf,
                                              const double* __restrict__ sums,
                                              const float* __restrict__ patch,
                                              float4* __restrict__ out4) {
  #pragma clang fp contract(off)
  __shared__ float bp[192];
  __shared__ int cand[13];     // cand[0]=count, then box indices (desc order)
  __shared__ float s_dm;
  int b = blockIdx.y;
  if (threadIdx.x < 192) bp[threadIdx.x] = params[b * 192 + threadIdx.x];
  __syncthreads();
  if (threadIdx.x == 0) {
    // block pixel range -> row range
    int pix_first = blockIdx.x * 1024;
    int y_first = pix_first / 640;
    int y_last  = (pix_first + 1023) / 640;
    float yl = (float)y_first, yh = (float)y_last;
    int cnt = 0;
    for (int n = 11; n >= 0; --n) {
      const float* Pp = &bp[n * 16];
      if (Pp[9] == 0.0f) continue;
      float y0f = Pp[0], diagf = Pp[2];
      // box rows [y0f, y0f+diagf) overlap [yl, yh]?
      if (yh < y0f || yl >= __fadd_rn(y0f, diagf)) continue;
      cand[1 + cnt] = n; ++cnt;
    }
    cand[0] = cnt;
    float mi = (float)(sums[b] / (double)IMG_ELEMS);
    float mp = (float)(sums[8 + b] / (double)PATCH_ELEMS);
    s_dm = __fsub_rn(mi, mp);
  }
  __syncthreads();
  int ncand = cand[0];

  int pix0 = blockIdx.x * 1024 + threadIdx.x * 4;      // 4 pixels, same row
  int y = pix0 / 640;
  int x0 = pix0 - y * 640;
  float yf = (float)y;

  // load background (always; patched regions overwritten below)
  size_t base4 = ((size_t)b * NPIX + (size_t)pix0) * 3u / 4u;  // 3 float4s
  float4 o0 = img4[base4], o1 = img4[base4 + 1], o2 = img4[base4 + 2];
  float ov[12] = {o0.x, o0.y, o0.z, o0.w, o1.x, o1.y, o1.z, o1.w,
                  o2.x, o2.y, o2.z, o2.w};

  if (ncand > 0) {
    float dm = s_dm;
    const float* wb = wsf + WB_OFF + b * 8;
    #pragma unroll
    for (int j = 0; j < 4; ++j) {
      float xf = (float)(x0 + j);
      int winner = -1;
      float ry = 0.0f, rx = 0.0f;
      for (int ci = 0; ci < ncand; ++ci) {
        int n = cand[1 + ci];
        const float* Pp = &bp[n * 16];
        float u = __fsub_rn(yf, Pp[0]);                 // exact (ints)
        float v = __fsub_rn(xf, Pp[1]);
        float diagf = Pp[2];
        if (!(u >= 0.0f && u < diagf && v >= 0.0f && v < diagf)) continue;
        float cc = Pp[5], ca = Pp[6], sa = Pp[7];
        float vc = __fsub_rn(v, cc), uc = __fsub_rn(u, cc);
        float sv = __fadd_rn(__fsub_rn(__fmul_rn(ca, vc), __fmul_rn(sa, uc)), cc);
        float su = __fadd_rn(__fadd_rn(__fmul_rn(sa, vc), __fmul_rn(ca, uc)), cc);
        float top = Pp[4], phf = Pp[3];
        float ry_ = __fsub_rn(su, top);
        float rx_ = __fsub_rn(sv, top);
        float ph1 = __fsub_rn(phf, 1.0f);
        if (!(ry_ >= 0.0f && ry_ <= ph1 && rx_ >= 0.0f && rx_ <= ph1)) continue;
        winner = n; ry = ry_; rx = rx_;
        break;
      }
      if (winner >= 0) {
        const float* Pp = &bp[winner * 16];
        float q = Pp[12], delta = Pp[8];
        uint32_t kn0 = __float_as_uint(Pp[10]), kn1 = __float_as_uint(Pp[11]);
        float py = __fsub_rn(__fmul_rn(__fadd_rn(ry, 0.5f), q), 0.5f);
        float px = __fsub_rn(__fmul_rn(__fadd_rn(rx, 0.5f), q), 0.5f);
        float fy = floorf(py), fx = floorf(px);
        float wy = __fsub_rn(py, fy), wx = __fsub_rn(px, fx);
        int y0i = min(max((int)fy, 0), 255);
        int x0i = min(max((int)fx, 0), 255);
        int y1i = min(y0i + 1, 255);
        int x1i = min(x0i + 1, 255);
        int i00 = (y0i * 256 + x0i) * 3, i01 = (y0i * 256 + x1i) * 3;
        int i10 = (y1i * 256 + x0i) * 3, i11 = (y1i * 256 + x1i) * 3;
        float omwx = __fsub_rn(1.0f, wx), omwy = __fsub_rn(1.0f, wy);
        int pix = pix0 + j;
        #pragma unroll
        for (int ch = 0; ch < 3; ++ch) {
          float wmc = wb[ch], bdc = wb[4 + ch];
          float v00 = fminf(fmaxf(__fadd_rn(fminf(fmaxf(__fadd_rn(__fmul_rn(wmc, patch[i00 + ch]), bdc), -1.0f), 1.0f), dm), -1.0f), 1.0f);
          float v01 = fminf(fmaxf(__fadd_rn(fminf(fmaxf(__fadd_rn(__fmul_rn(wmc, patch[i01 + ch]), bdc), -1.0f), 1.0f), dm), -1.0f), 1.0f);
          float v10 = fminf(fmaxf(__fadd_rn(fminf(fmaxf(__fadd_rn(__fmul_rn(wmc, patch[i10 + ch]), bdc), -1.0f), 1.0f), dm), -1.0f), 1.0f);
          float v11 = fminf(fmaxf(__fadd_rn(fminf(fmaxf(__fadd_rn(__fmul_rn(wmc, patch[i11 + ch]), bdc), -1.0f), 1.0f), dm), -1.0f), 1.0f);
          float t_ = __fadd_rn(__fmul_rn(omwx, v00), __fmul_rn(wx, v01));
          float b_ = __fadd_rn(__fmul_rn(omwx, v10), __fmul_rn(wx, v11));
          float bil = __fadd_rn(__fmul_rn(omwy, t_), __fmul_rn(wy, b_));
          uint32_t ni = (uint32_t)pix * 3u + (uint32_t)ch;
          float nf = u01(rbits32(kn0, kn1, ni));
          float noise = fmaxf(-0.01f, __fadd_rn(__fmul_rn(nf, 0.02f), -0.01f));
          float val = __fadd_rn(__fadd_rn(bil, noise), delta);
          ov[j * 3 + ch] = fminf(fmaxf(val, -1.0f), 1.0f);
        }
      }
    }
  }
  out4[base4]     = make_float4(ov[0], ov[1], ov[2], ov[3]);
  out4[base4 + 1] = make_float4(ov[4], ov[5], ov[6], ov[7]);
  out4[base4 + 2] = make_float4(ov[8], ov[9], ov[10], ov[11]);
}

// ---------------------------------------------------------------------------
extern "C" void kernel_launch(void* const* d_in, const int* in_sizes, int n_in,
                              void* d_out, int out_size, void* d_ws, size_t ws_size,
                              hipStream_t stream) {
  const float* images = (const float*)d_in[0];
  const float* boxes  = (const float*)d_in[1];
  const float* patch  = (const float*)d_in[2];
  const float* scale  = (const float*)d_in[3];
  float* wsf = (float*)d_ws;
  double* sums = (double*)d_ws;

  hipLaunchKernelGGL(k_params, dim3(1), dim3(128), 0, stream, boxes, scale, wsf);
  hipLaunchKernelGGL(k_sums, dim3(128, 8), dim3(256), 0, stream,
                     (const float4*)images, (const float4*)patch, wsf, sums);
  hipLaunchKernelGGL(k_main, dim3(400, 8), dim3(256), 0, stream,
                     (const float4*)images, wsf + BP_OFF, wsf, sums, patch,
                     (float4*)d_out);
}

// Round 5
// 126.594 us; speedup vs baseline: 1.6132x; 1.0832x over previous
//
#include <hip/hip_runtime.h>
#include <stdint.h>

// ---------------------------------------------------------------------------
// Patcher: bit-exact JAX threefry (partitionable scheme) + last-writer-wins
// composite. B=8, H=W=640, N=12 boxes, P=256 patch.
//
// R5: 2 dispatches. k_sums grid (129,8): bx<120 image-mean partials,
// bx==120 params block (box params + wmul/badd -> ws, f64 sincos exact),
// bx>120 patch-adjust-sum partials (wmul/badd recomputed inline -> no
// cross-block ordering needed). Partial sums in distinct ws slots (no
// atomics, no zero-init). k_main reduces partials with wave shuffles.
// Per-pixel float math unchanged (bit-identical) -> absmax stays at bf16 floor.
//
// ws doubles [0..1023]:  [b*120+i] img partials, [960+b*8+j] patch partials
// ws floats: [2048..2111] per-image wmul[3],_,badd[3],_ ; [2112..3647] box
// params (8*12*16).
// ---------------------------------------------------------------------------

#define IMG_ELEMS   1228800   // 640*640*3
#define NPIX        409600    // 640*640
#define PATCH_ELEMS 196608    // 256*256*3
#define WB_OFF 2048
#define BP_OFF 2112

#define TF_R(r) { x0 += x1; x1 = (x1 << r) | (x1 >> (32 - r)); x1 ^= x0; }

__device__ __forceinline__ void tf2x32(uint32_t k0, uint32_t k1,
                                       uint32_t c0, uint32_t c1,
                                       uint32_t& o0, uint32_t& o1) {
  uint32_t k2 = k0 ^ k1 ^ 0x1BD11BDAu;
  uint32_t x0 = c0 + k0, x1 = c1 + k1;
  TF_R(13) TF_R(15) TF_R(26) TF_R(6)
  x0 += k1; x1 += k2 + 1u;
  TF_R(17) TF_R(29) TF_R(16) TF_R(24)
  x0 += k2; x1 += k0 + 2u;
  TF_R(13) TF_R(15) TF_R(26) TF_R(6)
  x0 += k0; x1 += k1 + 3u;
  TF_R(17) TF_R(29) TF_R(16) TF_R(24)
  x0 += k1; x1 += k2 + 4u;
  TF_R(13) TF_R(15) TF_R(26) TF_R(6)
  x0 += k2; x1 += k0 + 5u;
  o0 = x0; o1 = x1;
}

__device__ __forceinline__ void split_key(uint32_t k0, uint32_t k1, uint32_t j,
                                          uint32_t& o0, uint32_t& o1) {
  tf2x32(k0, k1, 0u, j, o0, o1);
}

__device__ __forceinline__ uint32_t rbits32(uint32_t k0, uint32_t k1, uint32_t i) {
  uint32_t o0, o1;
  tf2x32(k0, k1, 0u, i, o0, o1);
  return o0 ^ o1;
}

__device__ __forceinline__ float u01(uint32_t bits) {
  return __uint_as_float((bits >> 9) | 0x3f800000u) - 1.0f;
}

// XLA ErfInv f32 (Giles) — value-level only (feeds wmul/badd normals)
__device__ __forceinline__ float erfinv_f(float x) {
  #pragma clang fp contract(off)
  float w = -log1pf(-(x * x));
  float p;
  if (w < 5.0f) {
    w = w - 2.5f;
    p = 2.81022636e-08f;
    p = 3.43273939e-07f + p * w;
    p = -3.5233877e-06f + p * w;
    p = -4.39150654e-06f + p * w;
    p = 0.00021858087f + p * w;
    p = -0.00125372503f + p * w;
    p = -0.00417768164f + p * w;
    p = 0.246640727f + p * w;
    p = 1.50140941f + p * w;
  } else {
    w = sqrtf(w) - 3.0f;
    p = -0.000200214257f;
    p = 0.000100950558f + p * w;
    p = 0.00134934322f + p * w;
    p = -0.00367342844f + p * w;
    p = 0.00573950773f + p * w;
    p = -0.0076224613f + p * w;
    p = 0.00943887047f + p * w;
    p = 1.00167406f + p * w;
    p = 2.83297682f + p * w;
  }
  return p * x;
}

// per-image wmul/badd channel values (identical formula everywhere)
__device__ __forceinline__ void wb_compute(int b, float* wm, float* bd) {
  #pragma clang fp contract(off)
  uint32_t ik0, ik1; split_key(0u, 42u, (uint32_t)b, ik0, ik1);
  uint32_t kw0, kw1; split_key(ik0, ik1, 0u, kw0, kw1);
  uint32_t kb0, kb1; split_key(ik0, ik1, 1u, kb0, kb1);
  const float lo  = __uint_as_float(0xBF7FFFFFu);   // nextafter(-1,0) f32
  const float SQ2 = (float)1.4142135623730951;
  for (int c = 0; c < 3; ++c) {
    float f  = u01(rbits32(kw0, kw1, (uint32_t)c));
    float u  = fmaxf(lo, __fadd_rn(__fmul_rn(f, 2.0f), lo));
    wm[c] = __fadd_rn(0.5f, __fmul_rn(0.1f, __fmul_rn(SQ2, erfinv_f(u))));
    float f2 = u01(rbits32(kb0, kb1, (uint32_t)c));
    float u2 = fmaxf(lo, __fadd_rn(__fmul_rn(f2, 2.0f), lo));
    bd[c] = __fmul_rn(0.01f, __fmul_rn(SQ2, erfinv_f(u2)));
  }
}

// ---------------------------------------------------------------------------
// K1: fused. bx<120: img-mean partial. bx==120: params block (ws writer).
// bx in 121..128: patch-adjust-sum partial (inline wmul/badd).
// ---------------------------------------------------------------------------
__global__ __launch_bounds__(256) void k_sums(const float4* __restrict__ img,
                                              const float4* __restrict__ patch,
                                              const float* __restrict__ boxes,
                                              const float* __restrict__ scale_p,
                                              float* __restrict__ wsf) {
  #pragma clang fp contract(off)
  int b = blockIdx.y;
  int bx = blockIdx.x;
  double* Pd = (double*)wsf;
  int tid = threadIdx.x;

  if (bx == 120) {
    if (b != 0) return;                 // params written once
    float scale = scale_p[0];
    if (tid < 8) {
      float wm[3], bd[3];
      wb_compute(tid, wm, bd);
      #pragma unroll
      for (int c = 0; c < 3; ++c) {
        wsf[WB_OFF + tid * 8 + c] = wm[c];
        wsf[WB_OFF + tid * 8 + 4 + c] = bd[c];
      }
    }
    if (tid >= 32 && tid < 128) {
      int t = tid - 32;
      int ib = t / 12, n = t % 12;
      uint32_t ik0, ik1; split_key(0u, 42u, (uint32_t)ib, ik0, ik1);
      uint32_t ks0, ks1; split_key(ik0, ik1, 2u, ks0, ks1);
      uint32_t bk0, bk1; split_key(ks0, ks1, (uint32_t)n, bk0, bk1);
      uint32_t kc10, kc11; split_key(bk0, bk1, 0u, kc10, kc11);
      uint32_t kc20, kc21; split_key(bk0, bk1, 1u, kc20, kc21);
      uint32_t ka0,  ka1;  split_key(bk0, bk1, 2u, ka0,  ka1);
      uint32_t kd0,  kd1;  split_key(bk0, bk1, 3u, kd0,  kd1);
      uint32_t kn0,  kn1;  split_key(bk0, bk1, 4u, kn0,  kn1);

      const float* bxp = boxes + (ib * 12 + n) * 4;
      float ymin = bxp[0], xmin = bxp[1], ymax = bxp[2], xmax = bxp[3];
      float h  = __fsub_rn(ymax, ymin);
      float ww = __fsub_rn(xmax, xmin);
      float longer = fmaxf(h, ww);
      float patch_size = floorf(__fmul_rn(longer, scale));
      float diag = fminf(__fmul_rn((float)1.41421356237, patch_size), 640.0f);
      float u1 = u01(rbits32(kc10, kc11, 0u));
      float u2 = u01(rbits32(kc20, kc21, 0u));
      float jy = __fmul_rn(__fmul_rn(__fsub_rn(u1, 0.5f), 0.2f), h);
      float jx = __fmul_rn(__fmul_rn(__fsub_rn(u2, 0.5f), 0.2f), ww);
      float oy = __fadd_rn(__fadd_rn(ymin, __fmul_rn(h, 0.5f)), jy);
      float ox = __fadd_rn(__fadd_rn(xmin, __fmul_rn(ww, 0.5f)), jx);
      float ymin_p = fmaxf(__fsub_rn(oy, __fmul_rn(diag, 0.5f)), 0.0f);
      float xmin_p = fmaxf(__fsub_rn(ox, __fmul_rn(diag, 0.5f)), 0.0f);
      ymin_p = (__fadd_rn(ymin_p, diag) > 640.0f) ? __fsub_rn(640.0f, diag) : ymin_p;
      xmin_p = (__fadd_rn(xmin_p, diag) > 640.0f) ? __fsub_rn(640.0f, diag) : xmin_p;
      float valid = (__fmul_rn(patch_size, patch_size) > 4.0f) ? 1.0f : 0.0f;
      float y0f = floorf(ymin_p), x0f = floorf(xmin_p);
      float phf = patch_size, diagf = floorf(diag);
      float top = floorf(__fmul_rn(__fsub_rn(diagf, phf), 0.5f));
      float ua = u01(rbits32(ka0, ka1, 0u));
      float angle = __fmul_rn(__fsub_rn(__fmul_rn(ua, 2.0f), 1.0f),
                              (float)0.3490658503988659);
      float ud = u01(rbits32(kd0, kd1, 0u));
      float delta = __fmul_rn(__fsub_rn(__fmul_rn(ud, 2.0f), 1.0f), 0.3f);
      float cc = __fmul_rn(__fsub_rn(diagf, 1.0f), 0.5f);
      float ca = (float)cos((double)angle);  // f64->f32 == correctly-rounded
      float sa = (float)sin((double)angle);
      float safe_ph = fmaxf(phf, 1.0f);
      float q = __fdiv_rn(256.0f, safe_ph);

      float* Pp = wsf + BP_OFF + (ib * 12 + n) * 16;
      Pp[0] = y0f;  Pp[1] = x0f;  Pp[2] = diagf; Pp[3] = phf;
      Pp[4] = top;  Pp[5] = cc;   Pp[6] = ca;    Pp[7] = sa;
      Pp[8] = delta; Pp[9] = valid;
      Pp[10] = __uint_as_float(kn0); Pp[11] = __uint_as_float(kn1);
      Pp[12] = q;
    }
    return;
  }

  double s = 0.0;
  int slot;
  if (bx < 120) {
    slot = b * 120 + bx;
    const float4* p = img + (size_t)b * (IMG_ELEMS / 4);
    const uint32_t stride = 120u * 256u;
    for (uint32_t i = bx * 256u + tid; i < (uint32_t)(IMG_ELEMS / 4); i += stride) {
      float4 v = p[i];
      s += (double)v.x + (double)v.y + (double)v.z + (double)v.w;
    }
  } else {
    slot = 960 + b * 8 + (bx - 121);
    __shared__ float pwb[8];
    if (tid == 0) {
      float wm[3], bd[3];
      wb_compute(b, wm, bd);
      #pragma unroll
      for (int c = 0; c < 3; ++c) { pwb[c] = wm[c]; pwb[4 + c] = bd[c]; }
    }
    __syncthreads();
    float wm[3] = {pwb[0], pwb[1], pwb[2]};
    float bd[3] = {pwb[4], pwb[5], pwb[6]};
    const uint32_t stride = 8u * 256u;
    for (uint32_t i = (bx - 121u) * 256u + tid; i < (uint32_t)(PATCH_ELEMS / 4);
         i += stride) {
      float4 v = patch[i];
      uint32_t c = (4u * i) % 3u;
      float f[4] = {v.x, v.y, v.z, v.w};
      #pragma unroll
      for (int j = 0; j < 4; ++j) {
        float val = __fadd_rn(__fmul_rn(wm[c], f[j]), bd[c]);
        val = fminf(fmaxf(val, -1.0f), 1.0f);
        s += (double)val;
        c = (c == 2u) ? 0u : (c + 1u);
      }
    }
  }
  for (int off = 32; off > 0; off >>= 1) s += __shfl_down(s, off, 64);
  __shared__ double sd[4];
  if ((tid & 63) == 0) sd[tid >> 6] = s;
  __syncthreads();
  if (tid == 0) Pd[slot] = sd[0] + sd[1] + sd[2] + sd[3];
}

// ---------------------------------------------------------------------------
// K2: main composite — 4 pixels/thread, float4 I/O, per-block y-culled box
// list; partial-sum reduction via wave shuffles. Last covering box wins.
// ---------------------------------------------------------------------------
__global__ __launch_bounds__(256) void k_main(const float4* __restrict__ img4,
                                              const float* __restrict__ wsf,
                                              const float* __restrict__ patch,
                                              float4* __restrict__ out4) {
  #pragma clang fp contract(off)
  __shared__ float bp[192];
  __shared__ int cand[13];
  __shared__ float s_dm;
  __shared__ double s_tot[2];
  int b = blockIdx.y;
  int tid = threadIdx.x;
  const double* Pd = (const double*)wsf;
  const float* params = wsf + BP_OFF;
  if (tid < 192) bp[tid] = params[b * 192 + tid];
  if (tid >= 64 && tid < 128) {          // wave 1: image partials (120)
    int i = tid - 64;
    double s = Pd[b * 120 + i] + ((i + 64 < 120) ? Pd[b * 120 + i + 64] : 0.0);
    for (int off = 32; off > 0; off >>= 1) s += __shfl_down(s, off, 64);
    if (i == 0) s_tot[0] = s;
  }
  if (tid >= 128 && tid < 192) {         // wave 2: patch partials (8)
    int j = tid - 128;
    double s = (j < 8) ? Pd[960 + b * 8 + j] : 0.0;
    for (int off = 32; off > 0; off >>= 1) s += __shfl_down(s, off, 64);
    if (j == 0) s_tot[1] = s;
  }
  __syncthreads();
  if (tid == 0) {
    int pix_first = blockIdx.x * 1024;
    int y_first = pix_first / 640;
    int y_last  = (pix_first + 1023) / 640;
    float yl = (float)y_first, yh = (float)y_last;
    int cnt = 0;
    for (int n = 11; n >= 0; --n) {
      const float* Pp = &bp[n * 16];
      if (Pp[9] == 0.0f) continue;
      float y0f = Pp[0], diagf = Pp[2];
      if (yh < y0f || yl >= __fadd_rn(y0f, diagf)) continue;
      cand[1 + cnt] = n; ++cnt;
    }
    cand[0] = cnt;
    float mi = (float)(s_tot[0] / (double)IMG_ELEMS);
    float mp = (float)(s_tot[1] / (double)PATCH_ELEMS);
    s_dm = __fsub_rn(mi, mp);
  }
  __syncthreads();
  int ncand = cand[0];

  int pix0 = blockIdx.x * 1024 + tid * 4;        // 4 pixels, same row
  int y = pix0 / 640;
  int x0 = pix0 - y * 640;
  float yf = (float)y;

  size_t base4 = ((size_t)b * NPIX + (size_t)pix0) * 3u / 4u;  // 3 float4s
  float4 o0 = img4[base4], o1 = img4[base4 + 1], o2 = img4[base4 + 2];
  float ov[12] = {o0.x, o0.y, o0.z, o0.w, o1.x, o1.y, o1.z, o1.w,
                  o2.x, o2.y, o2.z, o2.w};

  if (ncand > 0) {
    float dm = s_dm;
    const float* wb = wsf + WB_OFF + b * 8;
    #pragma unroll
    for (int j = 0; j < 4; ++j) {
      float xf = (float)(x0 + j);
      int winner = -1;
      float ry = 0.0f, rx = 0.0f;
      for (int ci = 0; ci < ncand; ++ci) {
        int n = cand[1 + ci];
        const float* Pp = &bp[n * 16];
        float u = __fsub_rn(yf, Pp[0]);
        float v = __fsub_rn(xf, Pp[1]);
        float diagf = Pp[2];
        if (!(u >= 0.0f && u < diagf && v >= 0.0f && v < diagf)) continue;
        float cc = Pp[5], ca = Pp[6], sa = Pp[7];
        float vc = __fsub_rn(v, cc), uc = __fsub_rn(u, cc);
        float sv = __fadd_rn(__fsub_rn(__fmul_rn(ca, vc), __fmul_rn(sa, uc)), cc);
        float su = __fadd_rn(__fadd_rn(__fmul_rn(sa, vc), __fmul_rn(ca, uc)), cc);
        float top = Pp[4], phf = Pp[3];
        float ry_ = __fsub_rn(su, top);
        float rx_ = __fsub_rn(sv, top);
        float ph1 = __fsub_rn(phf, 1.0f);
        if (!(ry_ >= 0.0f && ry_ <= ph1 && rx_ >= 0.0f && rx_ <= ph1)) continue;
        winner = n; ry = ry_; rx = rx_;
        break;
      }
      if (winner >= 0) {
        const float* Pp = &bp[winner * 16];
        float q = Pp[12], delta = Pp[8];
        uint32_t kn0 = __float_as_uint(Pp[10]), kn1 = __float_as_uint(Pp[11]);
        float py = __fsub_rn(__fmul_rn(__fadd_rn(ry, 0.5f), q), 0.5f);
        float px = __fsub_rn(__fmul_rn(__fadd_rn(rx, 0.5f), q), 0.5f);
        float fy = floorf(py), fx = floorf(px);
        float wy = __fsub_rn(py, fy), wx = __fsub_rn(px, fx);
        int y0i = min(max((int)fy, 0), 255);
        int x0i = min(max((int)fx, 0), 255);
        int y1i = min(y0i + 1, 255);
        int x1i = min(x0i + 1, 255);
        int i00 = (y0i * 256 + x0i) * 3, i01 = (y0i * 256 + x1i) * 3;
        int i10 = (y1i * 256 + x0i) * 3, i11 = (y1i * 256 + x1i) * 3;
        float omwx = __fsub_rn(1.0f, wx), omwy = __fsub_rn(1.0f, wy);
        int pix = pix0 + j;
        #pragma unroll
        for (int ch = 0; ch < 3; ++ch) {
          float wmc = wb[ch], bdc = wb[4 + ch];
          float v00 = fminf(fmaxf(__fadd_rn(fminf(fmaxf(__fadd_rn(__fmul_rn(wmc, patch[i00 + ch]), bdc), -1.0f), 1.0f), dm), -1.0f), 1.0f);
          float v01 = fminf(fmaxf(__fadd_rn(fminf(fmaxf(__fadd_rn(__fmul_rn(wmc, patch[i01 + ch]), bdc), -1.0f), 1.0f), dm), -1.0f), 1.0f);
          float v10 = fminf(fmaxf(__fadd_rn(fminf(fmaxf(__fadd_rn(__fmul_rn(wmc, patch[i10 + ch]), bdc), -1.0f), 1.0f), dm), -1.0f), 1.0f);
          float v11 = fminf(fmaxf(__fadd_rn(fminf(fmaxf(__fadd_rn(__fmul_rn(wmc, patch[i11 + ch]), bdc), -1.0f), 1.0f), dm), -1.0f), 1.0f);
          float t_ = __fadd_rn(__fmul_rn(omwx, v00), __fmul_rn(wx, v01));
          float b_ = __fadd_rn(__fmul_rn(omwx, v10), __fmul_rn(wx, v11));
          float bil = __fadd_rn(__fmul_rn(omwy, t_), __fmul_rn(wy, b_));
          uint32_t ni = (uint32_t)pix * 3u + (uint32_t)ch;
          float nf = u01(rbits32(kn0, kn1, ni));
          float noise = fmaxf(-0.01f, __fadd_rn(__fmul_rn(nf, 0.02f), -0.01f));
          float val = __fadd_rn(__fadd_rn(bil, noise), delta);
          ov[j * 3 + ch] = fminf(fmaxf(val, -1.0f), 1.0f);
        }
      }
    }
  }
  out4[base4]     = make_float4(ov[0], ov[1], ov[2], ov[3]);
  out4[base4 + 1] = make_float4(ov[4], ov[5], ov[6], ov[7]);
  out4[base4 + 2] = make_float4(ov[8], ov[9], ov[10], ov[11]);
}

// ---------------------------------------------------------------------------
extern "C" void kernel_launch(void* const* d_in, const int* in_sizes, int n_in,
                              void* d_out, int out_size, void* d_ws, size_t ws_size,
                              hipStream_t stream) {
  const float* images = (const float*)d_in[0];
  const float* boxes  = (const float*)d_in[1];
  const float* patch  = (const float*)d_in[2];
  const float* scale  = (const float*)d_in[3];
  float* wsf = (float*)d_ws;

  hipLaunchKernelGGL(k_sums, dim3(129, 8), dim3(256), 0, stream,
                     (const float4*)images, (const float4*)patch, boxes, scale,
                     wsf);
  hipLaunchKernelGGL(k_main, dim3(400, 8), dim3(256), 0, stream,
                     (const float4*)images, wsf, patch, (float4*)d_out);
}